// Round 6
// baseline (323.351 us; speedup 1.0000x reference)
//
#include <hip/hip_runtime.h>

#define NN 50000
#define NE 800000
#define D  128

typedef _Float16 f16;
typedef _Float16 f16x4 __attribute__((ext_vector_type(4)));
typedef _Float16 f16x8 __attribute__((ext_vector_type(8)));
typedef float f32x4 __attribute__((ext_vector_type(4)));
typedef float f32x2 __attribute__((ext_vector_type(2)));
typedef unsigned short u16;
typedef unsigned int u32;
typedef unsigned char u8;

// ---------------- prep: converts + degree count/rank ----------------
// blocks [0,6250): x -> xf (f16) and split fp8 slices lo/hi
// [6250,6346): 6 weight mats f32->f16
// [6346,9471): count_deg_rank (deg[] pre-zeroed by hipMemsetAsync)
__global__ __launch_bounds__(256) void prep(
    const float* __restrict__ x, f16* __restrict__ xf,
    u8* __restrict__ f8lo, u8* __restrict__ f8hi,
    const float* w0, const float* w1, const float* w2,
    const float* w3, const float* w4, const float* w5,
    f16* d0, f16* d1, f16* d2, f16* d3, f16* d4, f16* d5,
    const int* __restrict__ erow, int* __restrict__ deg, u16* __restrict__ rank) {
    int b = blockIdx.x;
    if (b < 6250) {
        int i = b * 256 + threadIdx.x;            // global float4 id
        float4 v = ((const float4*)x)[i];
        f16x4 o = {(f16)v.x, (f16)v.y, (f16)v.z, (f16)v.w};
        ((f16x4*)xf)[i] = o;
        u32 lo = __builtin_amdgcn_cvt_pk_fp8_f32(v.x, v.y, 0, false);
        u32 pk = __builtin_amdgcn_cvt_pk_fp8_f32(v.z, v.w, lo, true);
        int m = i >> 5, p4 = i & 31;              // row, float4-within-row
        u32* d8 = (u32*)(p4 < 16 ? f8lo : f8hi);
        d8[m * 16 + (p4 & 15)] = pk;
    } else if (b < 6346) {
        int wb = b - 6250;
        int mat = wb >> 4;
        const float* s; f16* d;
        switch (mat) {
            case 0: s = w0; d = d0; break; case 1: s = w1; d = d1; break;
            case 2: s = w2; d = d2; break; case 3: s = w3; d = d3; break;
            case 4: s = w4; d = d4; break; default: s = w5; d = d5; break;
        }
        int i = (wb & 15) * 256 + threadIdx.x;   // 0..4095 float4
        float4 v = ((const float4*)s)[i];
        f16x4 o = {(f16)v.x, (f16)v.y, (f16)v.z, (f16)v.w};
        ((f16x4*)d)[i] = o;
    } else {
        int i = (b - 6346) * 256 + threadIdx.x;   // < NE (3125*256 exactly)
        rank[i] = (u16)atomicAdd(&deg[erow[i]], 1);
    }
}

// ---------------- single-kernel segment allocation ----------------
// Segment ORDER across blocks is irrelevant (only per-node contiguity
// matters), so the block base comes from one atomicAdd of the block total.
__global__ __launch_bounds__(1024) void scan_offsets(
    const int* __restrict__ deg, int* __restrict__ cursor,
    int* __restrict__ offsets) {
    __shared__ int wsum[16];
    __shared__ int bbase;
    const int tid = threadIdx.x;
    const int w = tid >> 6, lane = tid & 63;
    const int i = blockIdx.x * 1024 + tid;
    int v = (i < NN) ? deg[i] : 0;
    int x = v;
#pragma unroll
    for (int m = 1; m < 64; m <<= 1) {
        int t = __shfl_up(x, m, 64);
        if (lane >= m) x += t;
    }
    if (lane == 63) wsum[w] = x;
    __syncthreads();
    if (w == 0) {
        int s = (lane < 16) ? wsum[lane] : 0;
#pragma unroll
        for (int m = 1; m < 16; m <<= 1) {
            int t = __shfl_up(s, m, 64);
            if (lane >= m) s += t;
        }
        if (lane < 16) wsum[lane] = s;
        if (lane == 15) bbase = atomicAdd(cursor, s);   // s = block total
    }
    __syncthreads();
    int excl = x - v + (w ? wsum[w - 1] : 0);
    if (i < NN) offsets[i] = bbase + excl;
}

__global__ __launch_bounds__(256) void fill_csr(
    const int* __restrict__ row, const int* __restrict__ col,
    const u16* __restrict__ rank, const int* __restrict__ offsets,
    u16* __restrict__ csr_col, int e) {
    int i = blockIdx.x * blockDim.x + threadIdx.x;
    if (i < e) {
        int p = offsets[row[i]] + (int)rank[i];
        csr_col[p] = (u16)col[i];
    }
}

// ---------------- mean aggregation, HALF-FEATURE pass ----------------
// slice = [NN][64] fp8 (3.2 MB -> fits a 4 MB per-XCD L2; the two passes run
// as separate launches so the whole GPU touches ONE slice at a time).
// Wave layout: sub = lane>>3 is the edge slot (8 edges/round), fl = lane&7
// the 8B feature octet -> 64B/row, 512B/wave-instr.
// Cols are pre-loaded once (coalesced csr[s0+lane]) and broadcast via __shfl,
// removing the csr read from the gather dependency chain.
// Output stores are nontemporal so the write stream doesn't evict the slice.
__global__ __launch_bounds__(256) void aggregate_half(
    const u8* __restrict__ slice, const int* __restrict__ offsets,
    const int* __restrict__ degv, const u16* __restrict__ csr,
    f16* __restrict__ agg, int half) {
    int node = blockIdx.x * 4 + (threadIdx.x >> 6);
    int lane = threadIdx.x & 63;
    int sub = lane >> 3, fl = lane & 7;
    int s0 = offsets[node];
    int deg = degv[node];

    int cl = 0;
    if (lane < deg) cl = (int)csr[s0 + lane];   // predicated coalesced preload

    float acc[8];
#pragma unroll
    for (int u = 0; u < 8; ++u) acc[u] = 0.f;

    const u8* hp = slice + fl * 8;

#define UNPACK_ADD(w)                                                  \
    do {                                                               \
        f32x2 p;                                                       \
        p = __builtin_amdgcn_cvt_pk_f32_fp8((w).x, false);             \
        acc[0] += p.x; acc[1] += p.y;                                  \
        p = __builtin_amdgcn_cvt_pk_f32_fp8((w).x, true);              \
        acc[2] += p.x; acc[3] += p.y;                                  \
        p = __builtin_amdgcn_cvt_pk_f32_fp8((w).y, false);             \
        acc[4] += p.x; acc[5] += p.y;                                  \
        p = __builtin_amdgcn_cvt_pk_f32_fp8((w).y, true);              \
        acc[6] += p.x; acc[7] += p.y;                                  \
    } while (0)

    int ng = deg <= 64 ? deg : 64;   // edges served by the shuffle path
    int e = sub;
    for (int it = ng >> 4; it > 0; --it, e += 16) {
        int c0 = __shfl(cl, e, 64);
        int c1 = __shfl(cl, e + 8, 64);
        uint2 w0 = *(const uint2*)(hp + (size_t)c0 * 64);
        uint2 w1 = *(const uint2*)(hp + (size_t)c1 * 64);
        UNPACK_ADD(w0);
        UNPACK_ADD(w1);
    }
    if (ng & 8) {
        int c0 = __shfl(cl, e, 64);
        uint2 w0 = *(const uint2*)(hp + (size_t)c0 * 64);
        UNPACK_ADD(w0);
        e += 8;
    }
    {
        int r = ng & 7;
        if (r) {
            int ec = (e < ng) ? e : (ng - 1);   // keep shuffle convergent
            int c = __shfl(cl, ec, 64);
            if (sub < r) {
                uint2 w = *(const uint2*)(hp + (size_t)c * 64);
                UNPACK_ADD(w);
            }
        }
    }
    if (deg > 64) {   // astronomically rare for random edges; correctness path
        for (int j = s0 + 64 + sub; j < s0 + deg; j += 8) {
            int c = (int)csr[j];
            uint2 w = *(const uint2*)(hp + (size_t)c * 64);
            UNPACK_ADD(w);
        }
    }
#undef UNPACK_ADD

    // reduce across the 8 edge slots (sub bits are lane bits 3,4,5)
#pragma unroll
    for (int u = 0; u < 8; ++u) {
        acc[u] += __shfl_xor(acc[u], 8, 64);
        acc[u] += __shfl_xor(acc[u], 16, 64);
        acc[u] += __shfl_xor(acc[u], 32, 64);
    }
    if (sub == 0) {
        float inv = 1.f / fmaxf((float)deg, 1.f);
        f16x8 o;
#pragma unroll
        for (int u = 0; u < 8; ++u) o[u] = (f16)(acc[u] * inv);
        __builtin_nontemporal_store(
            o, (f16x8*)(agg + (size_t)node * D + half * 64 + fl * 8));
    }
}

// ---------------- MFMA dual-GEMM, LDS-staged weights ----------------
// out[m][n] = sum_k agg[m][k]*Wl[n][k] + relu?(x[m][k])*Wr[n][k] + b[n] (+ x[m][n])
// When !OUT_F32 also writes split fp8(relu(out)) for the next layer's gather.
#define WPAD 72   // 64 + 8 f16 pad -> 144B row stride, <=2-way bank aliasing

template<int RELU_X, int ADD_RES, int OUT_F32>
__global__ __launch_bounds__(256, 4) void sage_gemm_mfma(
    const f16* __restrict__ aggb, const f16* __restrict__ xb,
    const f16* __restrict__ Wl, const f16* __restrict__ Wr,
    const float* __restrict__ bias, float* __restrict__ outf,
    f16* __restrict__ outh, u8* __restrict__ out8lo, u8* __restrict__ out8hi) {
    __shared__ f16 sW[2][128][WPAD];   // 36864 B

    const int tid  = threadIdx.x;
    const int wave = tid >> 6;
    const int lane = tid & 63;
    const int lm = lane & 15;
    const int q  = lane >> 4;
    const int mt = blockIdx.x * 64 + wave * 16;

    int row = mt + lm;
    int rclamp = (row < NN) ? row : NN - 1;

    // A fragments (full K), relu on x inline
    f16x8 Aa[4], Ax[4];
    const f16* arow = aggb + (size_t)rclamp * D + q * 8;
    const f16* xrow = xb  + (size_t)rclamp * D + q * 8;
#pragma unroll
    for (int ks = 0; ks < 4; ++ks) {
        Aa[ks] = *(const f16x8*)(arow + ks * 32);
        f16x8 v = *(const f16x8*)(xrow + ks * 32);
        if (RELU_X) {
#pragma unroll
            for (int u = 0; u < 8; ++u) v[u] = (v[u] < (f16)0) ? (f16)0 : v[u];
        }
        Ax[ks] = v;
    }

    f32x4 acc[8];
#pragma unroll
    for (int nt = 0; nt < 8; ++nt) acc[nt] = (f32x4){0.f, 0.f, 0.f, 0.f};

    for (int p = 0; p < 2; ++p) {
        __syncthreads();
        // stage Wl/Wr K-half: 2 mats x 128 n x 8 chunks of 16B = 2048 chunks
#pragma unroll
        for (int it = 0; it < 8; ++it) {
            int idx = tid + it * 256;
            int mat = idx >> 10;
            int n   = (idx >> 3) & 127;
            int c   = idx & 7;
            const f16* W = mat ? Wr : Wl;
            f16x8 v = *(const f16x8*)(W + n * D + p * 64 + c * 8);
            *(f16x8*)&sW[mat][n][c * 8] = v;
        }
        __syncthreads();

#pragma unroll
        for (int nt = 0; nt < 8; ++nt) {
#pragma unroll
            for (int k2 = 0; k2 < 2; ++k2) {
                f16x8 bl = *(const f16x8*)&sW[0][nt * 16 + lm][k2 * 32 + q * 8];
                acc[nt] = __builtin_amdgcn_mfma_f32_16x16x32_f16(Aa[p * 2 + k2], bl, acc[nt], 0, 0, 0);
                f16x8 br = *(const f16x8*)&sW[1][nt * 16 + lm][k2 * 32 + q * 8];
                acc[nt] = __builtin_amdgcn_mfma_f32_16x16x32_f16(Ax[p * 2 + k2], br, acc[nt], 0, 0, 0);
            }
        }
    }

    // epilogue: bias (+ f16 residual from xb). In-place outh==xb is safe:
    // each (m,n) is read & written by exactly one lane, rows owned by this wave.
#pragma unroll
    for (int nt = 0; nt < 8; ++nt) {
        int n = nt * 16 + lm;
        float bval = bias[n];
#pragma unroll
        for (int r = 0; r < 4; ++r) {
            int m = mt + q * 4 + r;
            if (m < NN) {
                size_t idx = (size_t)m * D + n;
                float v = acc[nt][r] + bval;
                if (ADD_RES) v += (float)xb[idx];
                if (OUT_F32) {
                    outf[idx] = v;
                } else {
                    outh[idx] = (f16)v;
                    u32 t = __builtin_amdgcn_cvt_pk_fp8_f32(fmaxf(v, 0.f), 0.f, 0, false);
                    u8* t8 = (n < 64) ? out8lo : out8hi;
                    t8[(size_t)m * 64 + (n & 63)] = (u8)(t & 0xffu);
                }
            }
        }
    }
}

// ---------------- launch ----------------

extern "C" void kernel_launch(void* const* d_in, const int* in_sizes, int n_in,
                              void* d_out, int out_size, void* d_ws, size_t ws_size,
                              hipStream_t stream) {
    const float* x    = (const float*)d_in[0];
    const int*   erow = (const int*)d_in[1];
    const int*   ecol = (const int*)d_in[2];
    const float* Wl0 = (const float*)d_in[3];
    const float* Wr0 = (const float*)d_in[4];
    const float* b0  = (const float*)d_in[5];
    const float* Wl1 = (const float*)d_in[6];
    const float* Wr1 = (const float*)d_in[7];
    const float* b1  = (const float*)d_in[8];
    const float* Wl2 = (const float*)d_in[9];
    const float* Wr2 = (const float*)d_in[10];
    const float* b2  = (const float*)d_in[11];

    char* ws = (char*)d_ws;
    size_t off = 0;
    auto carve = [&](size_t bytes) -> void* {
        void* p = ws + off;
        off = (off + bytes + 255) & ~(size_t)255;
        return p;
    };
    int*   deg     = (int*)carve((size_t)(NN + 1) * 4);   // deg[NN] = alloc cursor
    int*   offsets = (int*)carve((size_t)NN * 4);
    u16*   rank    = (u16*)carve((size_t)NE * 2);
    u16*   csr_col = (u16*)carve((size_t)NE * 2);
    f16*   xf      = (f16*)carve((size_t)NN * D * 2);
    f16*   x1      = (f16*)carve((size_t)NN * D * 2);
    f16*   aggb    = (f16*)carve((size_t)NN * D * 2);
    u8*    f8lo    = (u8*)carve((size_t)NN * 64);
    u8*    f8hi    = (u8*)carve((size_t)NN * 64);
    f16*   wl0 = (f16*)carve(D * D * 2); f16* wr0 = (f16*)carve(D * D * 2);
    f16*   wl1 = (f16*)carve(D * D * 2); f16* wr1 = (f16*)carve(D * D * 2);
    f16*   wl2 = (f16*)carve(D * D * 2); f16* wr2 = (f16*)carve(D * D * 2);
    (void)ws_size; (void)in_sizes; (void)n_in; (void)out_size;

    float* outp = (float*)d_out;

    // zero deg + cursor (graph-capturable memset node)
    (void)hipMemsetAsync(deg, 0, (size_t)(NN + 1) * 4, stream);

    // prep: converts + count/rank (6250 + 96 + 3125 blocks)
    prep<<<9471, 256, 0, stream>>>(x, xf, f8lo, f8hi, Wl0, Wr0, Wl1, Wr1, Wl2, Wr2,
                                   wl0, wr0, wl1, wr1, wl2, wr2,
                                   erow, deg, rank);

    // segment allocation (order-free block bases) + CSR fill
    const int nsb = (NN + 1023) / 1024;   // 49
    scan_offsets<<<nsb, 1024, 0, stream>>>(deg, deg + NN, offsets);
    fill_csr<<<(NE + 255) / 256, 256, 0, stream>>>(erow, ecol, rank, offsets, csr_col, NE);

    const int agrid = NN / 4;               // 12500, exact
    const int ggrid = (NN + 63) / 64;       // 782

    // fp8 is reused in place: agg reads complete before the gemm that
    // overwrites them (stream order), and gemm never reads fp8.
    // layer 0
    aggregate_half<<<agrid, 256, 0, stream>>>(f8lo, offsets, deg, csr_col, aggb, 0);
    aggregate_half<<<agrid, 256, 0, stream>>>(f8hi, offsets, deg, csr_col, aggb, 1);
    sage_gemm_mfma<0, 0, 0><<<ggrid, 256, 0, stream>>>(aggb, xf, wl0, wr0, b0,
                                                       nullptr, x1, f8lo, f8hi);
    // layer 1 (f16 residual in place)
    aggregate_half<<<agrid, 256, 0, stream>>>(f8lo, offsets, deg, csr_col, aggb, 0);
    aggregate_half<<<agrid, 256, 0, stream>>>(f8hi, offsets, deg, csr_col, aggb, 1);
    sage_gemm_mfma<1, 1, 0><<<ggrid, 256, 0, stream>>>(aggb, x1, wl1, wr1, b1,
                                                       nullptr, x1, f8lo, f8hi);
    // layer 2 (fp32 out)
    aggregate_half<<<agrid, 256, 0, stream>>>(f8lo, offsets, deg, csr_col, aggb, 0);
    aggregate_half<<<agrid, 256, 0, stream>>>(f8hi, offsets, deg, csr_col, aggb, 1);
    sage_gemm_mfma<1, 1, 1><<<ggrid, 256, 0, stream>>>(aggb, x1, wl2, wr2, b2,
                                                       outp, nullptr, nullptr, nullptr);
}

// Round 7
// 253.057 us; speedup vs baseline: 1.2778x; 1.2778x over previous
//
#include <hip/hip_runtime.h>

#define NN 50000
#define NE 800000
#define D  128

typedef _Float16 f16;
typedef _Float16 f16x4 __attribute__((ext_vector_type(4)));
typedef _Float16 f16x8 __attribute__((ext_vector_type(8)));
typedef float f32x4 __attribute__((ext_vector_type(4)));
typedef float f32x2 __attribute__((ext_vector_type(2)));
typedef unsigned short u16;
typedef unsigned int u32;
typedef unsigned char u8;

#define NB   64      // histogram blocks
#define ECH  12500   // NE / NB
#define NW   25000   // NN/2 packed u16-pair words

// ---------------- prep: converts only ----------------
// blocks [0,6250): x -> xf (f16) and xf8 (fp8); [6250,6346): 6 weight mats
__global__ __launch_bounds__(256) void prep(
    const float* __restrict__ x, f16* __restrict__ xf, u8* __restrict__ xf8,
    const float* w0, const float* w1, const float* w2,
    const float* w3, const float* w4, const float* w5,
    f16* d0, f16* d1, f16* d2, f16* d3, f16* d4, f16* d5) {
    int b = blockIdx.x;
    if (b < 6250) {
        int i = b * 256 + threadIdx.x;
        float4 v = ((const float4*)x)[i];
        f16x4 o = {(f16)v.x, (f16)v.y, (f16)v.z, (f16)v.w};
        ((f16x4*)xf)[i] = o;
        u32 lo = __builtin_amdgcn_cvt_pk_fp8_f32(v.x, v.y, 0, false);
        u32 pk = __builtin_amdgcn_cvt_pk_fp8_f32(v.z, v.w, lo, true);
        ((u32*)xf8)[i] = pk;
    } else {
        int wb = b - 6250;
        int mat = wb >> 4;
        const float* s; f16* d;
        switch (mat) {
            case 0: s = w0; d = d0; break; case 1: s = w1; d = d1; break;
            case 2: s = w2; d = d2; break; case 3: s = w3; d = d3; break;
            case 4: s = w4; d = d4; break; default: s = w5; d = d5; break;
        }
        int i = (wb & 15) * 256 + threadIdx.x;   // 0..4095 float4
        float4 v = ((const float4*)s)[i];
        f16x4 o = {(f16)v.x, (f16)v.y, (f16)v.z, (f16)v.w};
        ((f16x4*)d)[i] = o;
    }
}

// ---------------- CSR build via LDS-privatized histograms (NO global atomics) --
// Each block histograms its ECH edges in LDS (u16 pairs packed in u32; LDS
// atomicAdd's return value IS the edge's local rank), then flushes coalesced.
__global__ __launch_bounds__(1024) void hist64(
    const int* __restrict__ erow, u32* __restrict__ histw,
    u16* __restrict__ lrank, int* __restrict__ cursor) {
    __shared__ u32 lh[NW];   // 100 KB
    const int tid = threadIdx.x;
    for (int w = tid; w < NW; w += 1024) lh[w] = 0;
    if (blockIdx.x == 0 && tid == 0) *cursor = 0;   // for scan_offsets later
    __syncthreads();
    const int base = blockIdx.x * ECH;
    for (int k = tid; k < ECH; k += 1024) {
        int e = base + k;
        int r = erow[e];
        int sh = (r & 1) * 16;
        u32 old = atomicAdd(&lh[r >> 1], 1u << sh);
        lrank[e] = (u16)((old >> sh) & 0xffffu);   // per-(block,node) rank
    }
    __syncthreads();
    u32* hb = histw + blockIdx.x * NW;
    for (int w = tid; w < NW; w += 1024) hb[w] = lh[w];
}

// Per node: serial scan over the NB block-counts -> per-block segment base
// (u16, <= deg) and total degree. Adjacent threads share hist words (coalesced).
__global__ __launch_bounds__(256) void scan_cols(
    const u32* __restrict__ histw, u16* __restrict__ start16,
    int* __restrict__ deg) {
    int n = blockIdx.x * 256 + threadIdx.x;
    if (n >= NN) return;
    int sh = (n & 1) * 16;
    int s = 0;
    for (int b = 0; b < NB; ++b) {
        u32 wv = histw[b * NW + (n >> 1)];
        start16[b * NN + n] = (u16)s;
        s += (int)((wv >> sh) & 0xffffu);
    }
    deg[n] = s;
}

// ---------------- single-kernel segment allocation ----------------
// Segment ORDER across blocks is irrelevant (only per-node contiguity
// matters), so the block base comes from one atomicAdd of the block total.
__global__ __launch_bounds__(1024) void scan_offsets(
    const int* __restrict__ deg, int* __restrict__ cursor,
    int* __restrict__ offsets) {
    __shared__ int wsum[16];
    __shared__ int bbase;
    const int tid = threadIdx.x;
    const int w = tid >> 6, lane = tid & 63;
    const int i = blockIdx.x * 1024 + tid;
    int v = (i < NN) ? deg[i] : 0;
    int x = v;
#pragma unroll
    for (int m = 1; m < 64; m <<= 1) {
        int t = __shfl_up(x, m, 64);
        if (lane >= m) x += t;
    }
    if (lane == 63) wsum[w] = x;
    __syncthreads();
    if (w == 0) {
        int s = (lane < 16) ? wsum[lane] : 0;
#pragma unroll
        for (int m = 1; m < 16; m <<= 1) {
            int t = __shfl_up(s, m, 64);
            if (lane >= m) s += t;
        }
        if (lane < 16) wsum[lane] = s;
        if (lane == 15) bbase = atomicAdd(cursor, s);   // s = block total
    }
    __syncthreads();
    int excl = x - v + (w ? wsum[w - 1] : 0);
    if (i < NN) offsets[i] = bbase + excl;
}

// p = offsets[row] + start16[b][row] + lrank[e]. start16's random read hits a
// single 100 KB slice per edge-range (b is constant per fill block) -> L2-hot.
__global__ __launch_bounds__(256) void fill_csr(
    const int* __restrict__ row, const int* __restrict__ col,
    const u16* __restrict__ lrank, const u16* __restrict__ start16,
    const int* __restrict__ offsets, u16* __restrict__ csr_col) {
    int i = blockIdx.x * 256 + threadIdx.x;   // < NE exactly (3125*256)
    int r = row[i];
    int b = i / ECH;
    int p = offsets[r] + (int)start16[b * NN + r] + (int)lrank[i];
    csr_col[p] = (u16)col[i];
}

// ---------------- mean aggregation (fp8 gather, fp32 accumulate) ----------------
// One wave per node; sub = lane>>4 is the edge slot, fl = lane&15 the feature
// octet: 8B fp8 per lane -> one contiguous 128B request per edge. Main loop
// keeps 4 row-loads (16 edges) in flight per lane for latency hiding.
__global__ __launch_bounds__(256) void aggregate_f8(
    const u8* __restrict__ h8, const int* __restrict__ offsets,
    const int* __restrict__ degv, const u16* __restrict__ csr,
    f16* __restrict__ agg) {
    int node = blockIdx.x * 4 + (threadIdx.x >> 6);
    int lane = threadIdx.x & 63;
    int sub = lane >> 4, fl = lane & 15;
    int s0 = offsets[node];
    int deg = degv[node];

    float acc[8];
#pragma unroll
    for (int u = 0; u < 8; ++u) acc[u] = 0.f;

    const u8* hp = h8 + fl * 8;

#define UNPACK_ADD(w)                                                  \
    do {                                                               \
        f32x2 p;                                                       \
        p = __builtin_amdgcn_cvt_pk_f32_fp8((w).x, false);             \
        acc[0] += p.x; acc[1] += p.y;                                  \
        p = __builtin_amdgcn_cvt_pk_f32_fp8((w).x, true);              \
        acc[2] += p.x; acc[3] += p.y;                                  \
        p = __builtin_amdgcn_cvt_pk_f32_fp8((w).y, false);             \
        acc[4] += p.x; acc[5] += p.y;                                  \
        p = __builtin_amdgcn_cvt_pk_f32_fp8((w).y, true);              \
        acc[6] += p.x; acc[7] += p.y;                                  \
    } while (0)

    int j = s0 + sub;
    for (int it = deg >> 4; it > 0; --it, j += 16) {
        int c0 = (int)csr[j];
        int c1 = (int)csr[j + 4];
        int c2 = (int)csr[j + 8];
        int c3 = (int)csr[j + 12];
        uint2 w0 = *(const uint2*)(hp + (size_t)c0 * D);
        uint2 w1 = *(const uint2*)(hp + (size_t)c1 * D);
        uint2 w2 = *(const uint2*)(hp + (size_t)c2 * D);
        uint2 w3 = *(const uint2*)(hp + (size_t)c3 * D);
        UNPACK_ADD(w0);
        UNPACK_ADD(w1);
        UNPACK_ADD(w2);
        UNPACK_ADD(w3);
    }
    if (deg & 8) {
        int c0 = (int)csr[j];
        int c1 = (int)csr[j + 4];
        uint2 w0 = *(const uint2*)(hp + (size_t)c0 * D);
        uint2 w1 = *(const uint2*)(hp + (size_t)c1 * D);
        UNPACK_ADD(w0);
        UNPACK_ADD(w1);
        j += 8;
    }
    if (deg & 4) {
        int c = (int)csr[j];
        uint2 w = *(const uint2*)(hp + (size_t)c * D);
        UNPACK_ADD(w);
        j += 4;
    }
    if (sub < (deg & 3)) {
        int c = (int)csr[j];
        uint2 w = *(const uint2*)(hp + (size_t)c * D);
        UNPACK_ADD(w);
    }
#undef UNPACK_ADD

    // reduce across the 4 edge slots (lanes l, l^16, l^32, l^48)
#pragma unroll
    for (int u = 0; u < 8; ++u) {
        acc[u] += __shfl_xor(acc[u], 16, 64);
        acc[u] += __shfl_xor(acc[u], 32, 64);
    }
    if (sub == 0) {
        float inv = 1.f / fmaxf((float)deg, 1.f);
        f16x8 o;
#pragma unroll
        for (int u = 0; u < 8; ++u) o[u] = (f16)(acc[u] * inv);
        *((f16x8*)(agg + (size_t)node * D) + fl) = o;
    }
}

// ---------------- MFMA dual-GEMM, LDS-staged weights ----------------
// out[m][n] = sum_k agg[m][k]*Wl[n][k] + relu?(x[m][k])*Wr[n][k] + b[n] (+ x[m][n])
// When !OUT_F32 also writes out8 = fp8(relu(out)) for the next layer's gather.
#define WPAD 72   // 64 + 8 f16 pad -> 144B row stride, <=2-way bank aliasing

template<int RELU_X, int ADD_RES, int OUT_F32>
__global__ __launch_bounds__(256, 4) void sage_gemm_mfma(
    const f16* __restrict__ aggb, const f16* __restrict__ xb,
    const f16* __restrict__ Wl, const f16* __restrict__ Wr,
    const float* __restrict__ bias, float* __restrict__ outf,
    f16* __restrict__ outh, u8* __restrict__ out8) {
    __shared__ f16 sW[2][128][WPAD];   // 36864 B

    const int tid  = threadIdx.x;
    const int wave = tid >> 6;
    const int lane = tid & 63;
    const int lm = lane & 15;
    const int q  = lane >> 4;
    const int mt = blockIdx.x * 64 + wave * 16;

    int row = mt + lm;
    int rclamp = (row < NN) ? row : NN - 1;

    // A fragments (full K), relu on x inline
    f16x8 Aa[4], Ax[4];
    const f16* arow = aggb + (size_t)rclamp * D + q * 8;
    const f16* xrow = xb  + (size_t)rclamp * D + q * 8;
#pragma unroll
    for (int ks = 0; ks < 4; ++ks) {
        Aa[ks] = *(const f16x8*)(arow + ks * 32);
        f16x8 v = *(const f16x8*)(xrow + ks * 32);
        if (RELU_X) {
#pragma unroll
            for (int u = 0; u < 8; ++u) v[u] = (v[u] < (f16)0) ? (f16)0 : v[u];
        }
        Ax[ks] = v;
    }

    f32x4 acc[8];
#pragma unroll
    for (int nt = 0; nt < 8; ++nt) acc[nt] = (f32x4){0.f, 0.f, 0.f, 0.f};

    for (int p = 0; p < 2; ++p) {
        __syncthreads();
        // stage Wl/Wr K-half: 2 mats x 128 n x 8 chunks of 16B = 2048 chunks
#pragma unroll
        for (int it = 0; it < 8; ++it) {
            int idx = tid + it * 256;
            int mat = idx >> 10;
            int n   = (idx >> 3) & 127;
            int c   = idx & 7;
            const f16* W = mat ? Wr : Wl;
            f16x8 v = *(const f16x8*)(W + n * D + p * 64 + c * 8);
            *(f16x8*)&sW[mat][n][c * 8] = v;
        }
        __syncthreads();

#pragma unroll
        for (int nt = 0; nt < 8; ++nt) {
#pragma unroll
            for (int k2 = 0; k2 < 2; ++k2) {
                f16x8 bl = *(const f16x8*)&sW[0][nt * 16 + lm][k2 * 32 + q * 8];
                acc[nt] = __builtin_amdgcn_mfma_f32_16x16x32_f16(Aa[p * 2 + k2], bl, acc[nt], 0, 0, 0);
                f16x8 br = *(const f16x8*)&sW[1][nt * 16 + lm][k2 * 32 + q * 8];
                acc[nt] = __builtin_amdgcn_mfma_f32_16x16x32_f16(Ax[p * 2 + k2], br, acc[nt], 0, 0, 0);
            }
        }
    }

    // epilogue: bias (+ f16 residual from xb). In-place outh==xb is safe:
    // each (m,n) is read & written by exactly one lane, rows owned by this wave.
#pragma unroll
    for (int nt = 0; nt < 8; ++nt) {
        int n = nt * 16 + lm;
        float bval = bias[n];
#pragma unroll
        for (int r = 0; r < 4; ++r) {
            int m = mt + q * 4 + r;
            if (m < NN) {
                size_t idx = (size_t)m * D + n;
                float v = acc[nt][r] + bval;
                if (ADD_RES) v += (float)xb[idx];
                if (OUT_F32) {
                    outf[idx] = v;
                } else {
                    outh[idx] = (f16)v;
                    u32 t = __builtin_amdgcn_cvt_pk_fp8_f32(fmaxf(v, 0.f), 0.f, 0, false);
                    out8[idx] = (u8)(t & 0xffu);
                }
            }
        }
    }
}

// ---------------- launch ----------------

extern "C" void kernel_launch(void* const* d_in, const int* in_sizes, int n_in,
                              void* d_out, int out_size, void* d_ws, size_t ws_size,
                              hipStream_t stream) {
    const float* x    = (const float*)d_in[0];
    const int*   erow = (const int*)d_in[1];
    const int*   ecol = (const int*)d_in[2];
    const float* Wl0 = (const float*)d_in[3];
    const float* Wr0 = (const float*)d_in[4];
    const float* b0  = (const float*)d_in[5];
    const float* Wl1 = (const float*)d_in[6];
    const float* Wr1 = (const float*)d_in[7];
    const float* b1  = (const float*)d_in[8];
    const float* Wl2 = (const float*)d_in[9];
    const float* Wr2 = (const float*)d_in[10];
    const float* b2  = (const float*)d_in[11];

    char* ws = (char*)d_ws;
    size_t off = 0;
    auto carve = [&](size_t bytes) -> void* {
        void* p = ws + off;
        off = (off + bytes + 255) & ~(size_t)255;
        return p;
    };
    int*   deg     = (int*)carve((size_t)(NN + 1) * 4);   // deg[NN] = alloc cursor
    int*   offsets = (int*)carve((size_t)NN * 4);
    u32*   histw   = (u32*)carve((size_t)NB * NW * 4);    // 6.4 MB
    u16*   start16 = (u16*)carve((size_t)NB * NN * 2);    // 6.4 MB
    u16*   lrank   = (u16*)carve((size_t)NE * 2);
    u16*   csr_col = (u16*)carve((size_t)NE * 2);
    f16*   xf      = (f16*)carve((size_t)NN * D * 2);
    f16*   x1      = (f16*)carve((size_t)NN * D * 2);
    f16*   aggb    = (f16*)carve((size_t)NN * D * 2);
    u8*    xf8     = (u8*)carve((size_t)NN * D);
    u8*    x1f8    = (u8*)carve((size_t)NN * D);
    f16*   wl0 = (f16*)carve(D * D * 2); f16* wr0 = (f16*)carve(D * D * 2);
    f16*   wl1 = (f16*)carve(D * D * 2); f16* wr1 = (f16*)carve(D * D * 2);
    f16*   wl2 = (f16*)carve(D * D * 2); f16* wr2 = (f16*)carve(D * D * 2);
    (void)ws_size; (void)in_sizes; (void)n_in; (void)out_size;

    float* outp = (float*)d_out;

    // CSR build: LDS histograms -> column scan -> offsets -> fill (0 global atomics)
    hist64<<<NB, 1024, 0, stream>>>(erow, histw, lrank, deg + NN);
    // converts (independent of CSR; same stream so order is irrelevant)
    prep<<<6346, 256, 0, stream>>>(x, xf, xf8, Wl0, Wr0, Wl1, Wr1, Wl2, Wr2,
                                   wl0, wr0, wl1, wr1, wl2, wr2);
    scan_cols<<<(NN + 255) / 256, 256, 0, stream>>>(histw, start16, deg);
    const int nsb = (NN + 1023) / 1024;   // 49
    scan_offsets<<<nsb, 1024, 0, stream>>>(deg, deg + NN, offsets);
    fill_csr<<<NE / 256, 256, 0, stream>>>(erow, ecol, lrank, start16, offsets, csr_col);

    const int agrid = NN / 4;               // 12500, exact
    const int ggrid = (NN + 63) / 64;       // 782

    // layer 0: x1 = agg(x)@Wl0^T + x@Wr0^T + b0; x1f8 = fp8(relu(x1))
    aggregate_f8<<<agrid, 256, 0, stream>>>(xf8, offsets, deg, csr_col, aggb);
    sage_gemm_mfma<0, 0, 0><<<ggrid, 256, 0, stream>>>(aggb, xf, wl0, wr0, b0,
                                                       nullptr, x1, x1f8);
    // layer 1: x1 = agg(relu(x1))@Wl1^T + relu(x1)@Wr1^T + b1 + x1  (in place)
    aggregate_f8<<<agrid, 256, 0, stream>>>(x1f8, offsets, deg, csr_col, aggb);
    sage_gemm_mfma<1, 1, 0><<<ggrid, 256, 0, stream>>>(aggb, x1, wl1, wr1, b1,
                                                       nullptr, x1, x1f8);
    // layer 2: out = agg(relu(x1))@Wl2^T + relu(x1)@Wr2^T + b2 + x1  (fp32)
    aggregate_f8<<<agrid, 256, 0, stream>>>(x1f8, offsets, deg, csr_col, aggb);
    sage_gemm_mfma<1, 1, 1><<<ggrid, 256, 0, stream>>>(aggb, x1, wl2, wr2, b2,
                                                       outp, nullptr, nullptr);
}